// Round 3
// baseline (291.115 us; speedup 1.0000x reference)
//
#include <hip/hip_runtime.h>
#include <stdint.h>

typedef unsigned short u16;
typedef __attribute__((ext_vector_type(8))) short short8;
typedef __attribute__((ext_vector_type(4))) float floatx4;
typedef __attribute__((ext_vector_type(4))) unsigned short u16x4;

__device__ __forceinline__ float bf2f(u16 v) {
  union { uint32_t u; float f; } x; x.u = ((uint32_t)v) << 16; return x.f;
}
__device__ __forceinline__ u16 f2bf(float f) {
  union { float f; uint32_t u; } x; x.f = f;
  uint32_t r = x.u + 0x7fffu + ((x.u >> 16) & 1u);
  return (u16)(r >> 16);
}

// ------- transpose weights: fp32 in (R x C) -> bf16 out (C x R) ----------------
__global__ __launch_bounds__(256) void transpose_w_k(const float* __restrict__ in,
                                                     u16* __restrict__ out,
                                                     int R, int C) {
  __shared__ float tile[32][33];
  int c0 = blockIdx.x * 32, r0 = blockIdx.y * 32;
  int tx = threadIdx.x, ty = threadIdx.y;
#pragma unroll
  for (int i = 0; i < 32; i += 8)
    tile[ty + i][tx] = in[(size_t)(r0 + ty + i) * C + c0 + tx];
  __syncthreads();
#pragma unroll
  for (int i = 0; i < 32; i += 8)
    out[(size_t)(c0 + ty + i) * R + r0 + tx] = f2bf(tile[tx][ty + i]);
}

// ------- layernorm: 4096 rows x 1024, fp32 in -> bf16 out ----------------------
__global__ __launch_bounds__(256) void layernorm_k(const float* __restrict__ x,
                                                   const float* __restrict__ gamma,
                                                   const float* __restrict__ beta,
                                                   u16* __restrict__ xn) {
  int row = blockIdx.x;
  int t = threadIdx.x;
  const float* xr = x + (size_t)row * 1024;
  float4 xv = *(const float4*)(xr + t * 4);
  float v0 = xv.x, v1 = xv.y, v2 = xv.z, v3 = xv.w;
  float s = v0 + v1 + v2 + v3;
  float s2 = v0 * v0 + v1 * v1 + v2 * v2 + v3 * v3;
#pragma unroll
  for (int d = 1; d < 64; d <<= 1) {
    s += __shfl_xor(s, d, 64);
    s2 += __shfl_xor(s2, d, 64);
  }
  __shared__ float red[8];
  int lane = t & 63, wv = t >> 6;
  if (lane == 0) { red[wv] = s; red[4 + wv] = s2; }
  __syncthreads();
  s = red[0] + red[1] + red[2] + red[3];
  s2 = red[4] + red[5] + red[6] + red[7];
  float mu = s * (1.0f / 1024.0f);
  float var = s2 * (1.0f / 1024.0f) - mu * mu;
  float rstd = rsqrtf(var + 1e-5f);
  float4 gv = *(const float4*)(gamma + t * 4);
  float4 bv = *(const float4*)(beta + t * 4);
  u16x4 ov;
  ov.x = f2bf((v0 - mu) * rstd * gv.x + bv.x);
  ov.y = f2bf((v1 - mu) * rstd * gv.y + bv.y);
  ov.z = f2bf((v2 - mu) * rstd * gv.z + bv.z);
  ov.w = f2bf((v3 - mu) * rstd * gv.w + bv.w);
  *(u16x4*)(xn + (size_t)row * 1024 + t * 4) = ov;
}

// ------- GEMM: C[MxN] = A[MxK](bf16,lda) * BT[NxK](bf16)^T ---------------------
// 128x128 tile, 4 waves (2x2 of 64x64), BK=32, mfma 16x16x32 bf16.
// f32out=0: C bf16 (ldc). f32out=1: C fp32 (ldc).
#define LDT 40
__global__ __launch_bounds__(256) void gemm_bf16_k(const u16* __restrict__ A,
                                                   const u16* __restrict__ BT,
                                                   void* __restrict__ Cp,
                                                   int K, int lda, int ldc,
                                                   int f32out) {
  __shared__ __align__(16) u16 lA[128 * LDT];
  __shared__ __align__(16) u16 lB[128 * LDT];
  int tid = threadIdx.x;
  int bm = blockIdx.y * 128;
  int bn = blockIdx.x * 128;
  int w = tid >> 6, l = tid & 63;
  int wm = (w >> 1) * 64, wn = (w & 1) * 64;
  int lr = l & 15, lq = l >> 4;
  floatx4 acc[4][4] = {};
  int ar = tid >> 1;
  int ac = (tid & 1) * 16;
  for (int k0 = 0; k0 < K; k0 += 32) {
    const u16* ga = A + (size_t)(bm + ar) * lda + k0 + ac;
    short8 av0 = *(const short8*)(ga);
    short8 av1 = *(const short8*)(ga + 8);
    const u16* gb = BT + (size_t)(bn + ar) * K + k0 + ac;
    short8 bv0 = *(const short8*)(gb);
    short8 bv1 = *(const short8*)(gb + 8);
    *(short8*)(&lA[ar * LDT + ac]) = av0;
    *(short8*)(&lA[ar * LDT + ac + 8]) = av1;
    *(short8*)(&lB[ar * LDT + ac]) = bv0;
    *(short8*)(&lB[ar * LDT + ac + 8]) = bv1;
    __syncthreads();
    short8 afr[4], bfr[4];
#pragma unroll
    for (int i = 0; i < 4; i++)
      afr[i] = *(const short8*)(&lA[(wm + i * 16 + lr) * LDT + lq * 8]);
#pragma unroll
    for (int i = 0; i < 4; i++)
      bfr[i] = *(const short8*)(&lB[(wn + i * 16 + lr) * LDT + lq * 8]);
#pragma unroll
    for (int mi = 0; mi < 4; mi++)
#pragma unroll
      for (int ni = 0; ni < 4; ni++)
        acc[mi][ni] = __builtin_amdgcn_mfma_f32_16x16x32_bf16(
            afr[mi], bfr[ni], acc[mi][ni], 0, 0, 0);
    __syncthreads();
  }
  if (f32out) {
    float* Cf = (float*)Cp;
#pragma unroll
    for (int mi = 0; mi < 4; mi++)
#pragma unroll
      for (int ni = 0; ni < 4; ni++)
#pragma unroll
        for (int r = 0; r < 4; r++) {
          int row = bm + wm + mi * 16 + lq * 4 + r;
          int col = bn + wn + ni * 16 + lr;
          Cf[(size_t)row * ldc + col] = acc[mi][ni][r];
        }
  } else {
    u16* Cb = (u16*)Cp;
#pragma unroll
    for (int mi = 0; mi < 4; mi++)
#pragma unroll
      for (int ni = 0; ni < 4; ni++)
#pragma unroll
        for (int r = 0; r < 4; r++) {
          int row = bm + wm + mi * 16 + lq * 4 + r;
          int col = bn + wn + ni * 16 + lr;
          Cb[(size_t)row * ldc + col] = f2bf(acc[mi][ni][r]);
        }
  }
}

// ------- RoPE (in-place on bf16 qkv q,k slices) + q scale ----------------------
__global__ __launch_bounds__(256) void rope_inplace_k(u16* __restrict__ qkv) {
  int idx = blockIdx.x * 256 + threadIdx.x;  // (row*16 + h)*32 + i, row in [0,4096)
  int i = idx & 31;
  int h = (idx >> 5) & 15;
  int row = idx >> 9;
  int n = row & 2047;
  float invf = exp2f(-(float)i * 0.4152410118609203f);  // 10000^(-i/32)
  float ang = (float)n * invf;
  float c = cosf(ang), s = sinf(ang);
  size_t ibase = (size_t)row * 3072 + h * 64 + i;
  float x1 = bf2f(qkv[ibase]), x2 = bf2f(qkv[ibase + 32]);
  qkv[ibase] = f2bf((x1 * c - x2 * s) * 0.125f);
  qkv[ibase + 32] = f2bf((x2 * c + x1 * s) * 0.125f);
  x1 = bf2f(qkv[ibase + 1024]); x2 = bf2f(qkv[ibase + 1056]);
  qkv[ibase + 1024] = f2bf(x1 * c - x2 * s);
  qkv[ibase + 1056] = f2bf(x2 * c + x1 * s);
}

// ------- V transpose: qkv v-slice (n,64) -> vT (bh, 64, n), bf16 ---------------
__global__ __launch_bounds__(256) void transpose_v_k(const u16* __restrict__ qkv,
                                                     u16* __restrict__ vT) {
  __shared__ u16 tile[32][33];
  int bh = blockIdx.z;
  int b = bh >> 4, h = bh & 15;
  int n0 = blockIdx.x * 32, d0 = blockIdx.y * 32;
  int tx = threadIdx.x, ty = threadIdx.y;
#pragma unroll
  for (int i = 0; i < 32; i += 8)
    tile[ty + i][tx] =
        qkv[(size_t)(b * 2048 + n0 + ty + i) * 3072 + 2048 + h * 64 + d0 + tx];
  __syncthreads();
#pragma unroll
  for (int i = 0; i < 32; i += 8)
    vT[((size_t)bh * 64 + d0 + ty + i) * 2048 + n0 + tx] = tile[tx][ty + i];
}

// ------- flash attention (causal), bh=32, n=2048, d=64 -------------------------
// q at qkv col 0, k at qkv col 1024 (row stride 3072); out -> qkv col 2048 (bf16).
#define LKT 72
__global__ __launch_bounds__(256) void attn_k(const u16* __restrict__ qkv,
                                              const u16* __restrict__ vt,
                                              u16* __restrict__ out) {
  __shared__ __align__(16) u16 lK[64 * LKT];
  __shared__ __align__(16) u16 lV[64 * LKT];
  __shared__ __align__(16) u16 lP[4][16 * LKT];
  int bh = blockIdx.y;
  int b = bh >> 4, h = bh & 15;
  int qt = blockIdx.x;
  int tid = threadIdx.x;
  int w = tid >> 6, l = tid & 63;
  int lr = l & 15, lq = l >> 4;
  int q0 = qt * 64;
  const u16* qb = qkv + (size_t)b * 2048 * 3072 + h * 64;
  const u16* kb = qkv + (size_t)b * 2048 * 3072 + 1024 + h * 64;
  const u16* vb = vt + (size_t)bh * 64 * 2048;
  int qrow = q0 + w * 16 + lr;
  short8 aq[2];
  aq[0] = *(const short8*)(qb + (size_t)qrow * 3072 + lq * 8);
  aq[1] = *(const short8*)(qb + (size_t)qrow * 3072 + 32 + lq * 8);
  floatx4 o[4] = {};
  float m_i[4], l_i[4];
#pragma unroll
  for (int r = 0; r < 4; r++) { m_i[r] = -1e30f; l_i[r] = 0.0f; }
  int st_row = tid >> 2, st_c = (tid & 3) * 16;
  for (int kt = 0; kt <= qt; ++kt) {
    {
      const u16* gk = kb + (size_t)(kt * 64 + st_row) * 3072 + st_c;
      short8 k0v = *(const short8*)gk;
      short8 k1v = *(const short8*)(gk + 8);
      const u16* gv = vb + (size_t)st_row * 2048 + kt * 64 + st_c;
      short8 v0v = *(const short8*)gv;
      short8 v1v = *(const short8*)(gv + 8);
      *(short8*)&lK[st_row * LKT + st_c] = k0v;
      *(short8*)&lK[st_row * LKT + st_c + 8] = k1v;
      *(short8*)&lV[st_row * LKT + st_c] = v0v;
      *(short8*)&lV[st_row * LKT + st_c + 8] = v1v;
    }
    __syncthreads();
    floatx4 s[4];
#pragma unroll
    for (int ni = 0; ni < 4; ni++) {
      floatx4 accs = {};
#pragma unroll
      for (int kc = 0; kc < 2; kc++) {
        short8 bf = *(const short8*)&lK[(ni * 16 + lr) * LKT + kc * 32 + lq * 8];
        accs = __builtin_amdgcn_mfma_f32_16x16x32_bf16(aq[kc], bf, accs, 0, 0, 0);
      }
      s[ni] = accs;
    }
    if (kt == qt) {
#pragma unroll
      for (int ni = 0; ni < 4; ni++) {
        int kg = kt * 64 + ni * 16 + lr;
#pragma unroll
        for (int r = 0; r < 4; r++) {
          int qg = q0 + w * 16 + lq * 4 + r;
          if (kg > qg) s[ni][r] = -1e30f;
        }
      }
    }
    float mnew[4], alpha[4], psum[4];
#pragma unroll
    for (int r = 0; r < 4; r++) {
      float mx = fmaxf(fmaxf(s[0][r], s[1][r]), fmaxf(s[2][r], s[3][r]));
#pragma unroll
      for (int d = 1; d < 16; d <<= 1) mx = fmaxf(mx, __shfl_xor(mx, d, 64));
      mnew[r] = fmaxf(m_i[r], mx);
      alpha[r] = __expf(m_i[r] - mnew[r]);
      psum[r] = 0.0f;
    }
#pragma unroll
    for (int ni = 0; ni < 4; ni++)
#pragma unroll
      for (int r = 0; r < 4; r++) {
        float p = __expf(s[ni][r] - mnew[r]);
        s[ni][r] = p;
        psum[r] += p;
      }
#pragma unroll
    for (int r = 0; r < 4; r++) {
#pragma unroll
      for (int d = 1; d < 16; d <<= 1) psum[r] += __shfl_xor(psum[r], d, 64);
      l_i[r] = l_i[r] * alpha[r] + psum[r];
      m_i[r] = mnew[r];
    }
#pragma unroll
    for (int di = 0; di < 4; di++)
#pragma unroll
      for (int r = 0; r < 4; r++) o[di][r] *= alpha[r];
    u16* lp = &lP[w][0];
#pragma unroll
    for (int ni = 0; ni < 4; ni++)
#pragma unroll
      for (int r = 0; r < 4; r++)
        lp[(lq * 4 + r) * LKT + ni * 16 + lr] = f2bf(s[ni][r]);
    short8 pa0 = *(const short8*)&lp[lr * LKT + lq * 8];
    short8 pa1 = *(const short8*)&lp[lr * LKT + 32 + lq * 8];
#pragma unroll
    for (int di = 0; di < 4; di++) {
      short8 bv0 = *(const short8*)&lV[(di * 16 + lr) * LKT + lq * 8];
      o[di] = __builtin_amdgcn_mfma_f32_16x16x32_bf16(pa0, bv0, o[di], 0, 0, 0);
      short8 bv1 = *(const short8*)&lV[(di * 16 + lr) * LKT + 32 + lq * 8];
      o[di] = __builtin_amdgcn_mfma_f32_16x16x32_bf16(pa1, bv1, o[di], 0, 0, 0);
    }
    __syncthreads();
  }
#pragma unroll
  for (int di = 0; di < 4; di++)
#pragma unroll
    for (int r = 0; r < 4; r++) {
      int qg = q0 + w * 16 + lq * 4 + r;
      float val = o[di][r] / l_i[r];
      out[((size_t)(b * 2048 + qg)) * 3072 + h * 64 + di * 16 + lr] = f2bf(val);
    }
}

// ------- launch ---------------------------------------------------------------
extern "C" void kernel_launch(void* const* d_in, const int* in_sizes, int n_in,
                              void* d_out, int out_size, void* d_ws, size_t ws_size,
                              hipStream_t stream) {
  const float* x = (const float*)d_in[0];
  const float* gamma = (const float*)d_in[1];
  const float* beta = (const float*)d_in[2];
  const float* Wq = (const float*)d_in[3];
  const float* Wkv = (const float*)d_in[4];
  const float* Wo = (const float*)d_in[5];
  float* out = (float*)d_out;
  char* ws = (char*)d_ws;

  // Workspace (bf16, 40 MiB total):
  u16* qkv = (u16*)(ws);               // 4096x3072 bf16 = 24 MiB
  u16* wqkvT = (u16*)(ws + 25165824);  // 3072x1024 = 6 MiB
  u16* woT = (u16*)(ws + 31457280);    // 1024x1024 = 2 MiB
  u16* xn = (u16*)(ws + 33554432);     // 4096x1024 = 8 MiB
  u16* vT = xn;                        // alias: xn dead after GEMM1
  u16* attn_out = qkv + 2048;          // v-slice of qkv (dead after transpose_v)

  dim3 tb32(32, 8);
  transpose_w_k<<<dim3(32, 32), tb32, 0, stream>>>(Wq, wqkvT, 1024, 1024);
  transpose_w_k<<<dim3(64, 32), tb32, 0, stream>>>(Wkv, wqkvT + 1024 * 1024, 1024, 2048);
  transpose_w_k<<<dim3(32, 32), tb32, 0, stream>>>(Wo, woT, 1024, 1024);
  layernorm_k<<<4096, 256, 0, stream>>>(x, gamma, beta, xn);
  gemm_bf16_k<<<dim3(24, 32), 256, 0, stream>>>(xn, wqkvT, qkv, 1024, 1024, 3072, 0);
  rope_inplace_k<<<8192, 256, 0, stream>>>(qkv);
  transpose_v_k<<<dim3(64, 2, 32), tb32, 0, stream>>>(qkv, vT);
  attn_k<<<dim3(32, 32), 256, 0, stream>>>(qkv, vT, attn_out);
  gemm_bf16_k<<<dim3(8, 32), 256, 0, stream>>>(attn_out, woT, out, 1024, 3072, 1024, 1);
}

// Round 4
// 244.385 us; speedup vs baseline: 1.1912x; 1.1912x over previous
//
#include <hip/hip_runtime.h>
#include <stdint.h>

typedef unsigned short u16;
typedef __attribute__((ext_vector_type(8))) short short8;
typedef __attribute__((ext_vector_type(4))) float floatx4;
typedef __attribute__((ext_vector_type(4))) unsigned short u16x4;

__device__ __forceinline__ float bf2f(u16 v) {
  union { uint32_t u; float f; } x; x.u = ((uint32_t)v) << 16; return x.f;
}
__device__ __forceinline__ u16 f2bf(float f) {
  union { float f; uint32_t u; } x; x.f = f;
  uint32_t r = x.u + 0x7fffu + ((x.u >> 16) & 1u);
  return (u16)(r >> 16);
}

#define GL2LDS(g, l)                                                          \
  __builtin_amdgcn_global_load_lds(                                           \
      (const __attribute__((address_space(1))) void*)(g),                     \
      (__attribute__((address_space(3))) void*)(l), 16, 0, 0)

// ------- transpose weights: fp32 in (R x C) -> bf16 out (C x R) ----------------
__global__ __launch_bounds__(256) void transpose_w_k(const float* __restrict__ in,
                                                     u16* __restrict__ out,
                                                     int R, int C) {
  __shared__ float tile[32][33];
  int c0 = blockIdx.x * 32, r0 = blockIdx.y * 32;
  int tx = threadIdx.x, ty = threadIdx.y;
#pragma unroll
  for (int i = 0; i < 32; i += 8)
    tile[ty + i][tx] = in[(size_t)(r0 + ty + i) * C + c0 + tx];
  __syncthreads();
#pragma unroll
  for (int i = 0; i < 32; i += 8)
    out[(size_t)(c0 + ty + i) * R + r0 + tx] = f2bf(tile[tx][ty + i]);
}

// ------- layernorm: 4096 rows x 1024, fp32 in -> bf16 out ----------------------
__global__ __launch_bounds__(256) void layernorm_k(const float* __restrict__ x,
                                                   const float* __restrict__ gamma,
                                                   const float* __restrict__ beta,
                                                   u16* __restrict__ xn) {
  int row = blockIdx.x;
  int t = threadIdx.x;
  const float* xr = x + (size_t)row * 1024;
  float4 xv = *(const float4*)(xr + t * 4);
  float v0 = xv.x, v1 = xv.y, v2 = xv.z, v3 = xv.w;
  float s = v0 + v1 + v2 + v3;
  float s2 = v0 * v0 + v1 * v1 + v2 * v2 + v3 * v3;
#pragma unroll
  for (int d = 1; d < 64; d <<= 1) {
    s += __shfl_xor(s, d, 64);
    s2 += __shfl_xor(s2, d, 64);
  }
  __shared__ float red[8];
  int lane = t & 63, wv = t >> 6;
  if (lane == 0) { red[wv] = s; red[4 + wv] = s2; }
  __syncthreads();
  s = red[0] + red[1] + red[2] + red[3];
  s2 = red[4] + red[5] + red[6] + red[7];
  float mu = s * (1.0f / 1024.0f);
  float var = s2 * (1.0f / 1024.0f) - mu * mu;
  float rstd = rsqrtf(var + 1e-5f);
  float4 gv = *(const float4*)(gamma + t * 4);
  float4 bv = *(const float4*)(beta + t * 4);
  u16x4 ov;
  ov.x = f2bf((v0 - mu) * rstd * gv.x + bv.x);
  ov.y = f2bf((v1 - mu) * rstd * gv.y + bv.y);
  ov.z = f2bf((v2 - mu) * rstd * gv.z + bv.z);
  ov.w = f2bf((v3 - mu) * rstd * gv.w + bv.w);
  *(u16x4*)(xn + (size_t)row * 1024 + t * 4) = ov;
}

// ------- GEMM: C[MxN] = A[MxK](bf16,lda) * BT[NxK](bf16)^T ---------------------
// m97 structure: 128x128 tile, 4 waves, BK=32, global_load_lds width=16,
// unpadded LDS (lane-contiguous dest required by global_load_lds).
__global__ __launch_bounds__(256) void gemm_bf16_k(const u16* __restrict__ A,
                                                   const u16* __restrict__ BT,
                                                   void* __restrict__ Cp,
                                                   int K, int lda, int ldc,
                                                   int f32out) {
  __shared__ __align__(16) u16 lA[128 * 32];
  __shared__ __align__(16) u16 lB[128 * 32];
  int tid = threadIdx.x;
  int bm = blockIdx.y * 128;
  int bn = blockIdx.x * 128;
  int w = tid >> 6, l = tid & 63;
  int wm = (w >> 1) * 64, wn = (w & 1) * 64;
  int lr = l & 15, lq = l >> 4;
  floatx4 acc[4][4] = {};
  // staging: wave w, lane l -> row w*16 + (l>>2) (+64 for 2nd call), col (l&3)*8
  int sr = w * 16 + (l >> 2);
  int sc = (l & 3) * 8;
  for (int k0 = 0; k0 < K; k0 += 32) {
    GL2LDS(A + (size_t)(bm + sr) * lda + k0 + sc, &lA[sr * 32 + sc]);
    GL2LDS(A + (size_t)(bm + sr + 64) * lda + k0 + sc, &lA[(sr + 64) * 32 + sc]);
    GL2LDS(BT + (size_t)(bn + sr) * K + k0 + sc, &lB[sr * 32 + sc]);
    GL2LDS(BT + (size_t)(bn + sr + 64) * K + k0 + sc, &lB[(sr + 64) * 32 + sc]);
    __syncthreads();
    short8 afr[4], bfr[4];
#pragma unroll
    for (int i = 0; i < 4; i++)
      afr[i] = *(const short8*)(&lA[(wm + i * 16 + lr) * 32 + lq * 8]);
#pragma unroll
    for (int i = 0; i < 4; i++)
      bfr[i] = *(const short8*)(&lB[(wn + i * 16 + lr) * 32 + lq * 8]);
#pragma unroll
    for (int mi = 0; mi < 4; mi++)
#pragma unroll
      for (int ni = 0; ni < 4; ni++)
        acc[mi][ni] = __builtin_amdgcn_mfma_f32_16x16x32_bf16(
            afr[mi], bfr[ni], acc[mi][ni], 0, 0, 0);
    __syncthreads();
  }
  if (f32out) {
    float* Cf = (float*)Cp;
#pragma unroll
    for (int mi = 0; mi < 4; mi++)
#pragma unroll
      for (int ni = 0; ni < 4; ni++)
#pragma unroll
        for (int r = 0; r < 4; r++) {
          int row = bm + wm + mi * 16 + lq * 4 + r;
          int col = bn + wn + ni * 16 + lr;
          Cf[(size_t)row * ldc + col] = acc[mi][ni][r];
        }
  } else {
    u16* Cb = (u16*)Cp;
#pragma unroll
    for (int mi = 0; mi < 4; mi++)
#pragma unroll
      for (int ni = 0; ni < 4; ni++)
#pragma unroll
        for (int r = 0; r < 4; r++) {
          int row = bm + wm + mi * 16 + lq * 4 + r;
          int col = bn + wn + ni * 16 + lr;
          Cb[(size_t)row * ldc + col] = f2bf(acc[mi][ni][r]);
        }
  }
}

// ------- RoPE (in-place on bf16 qkv q,k slices) + q scale ----------------------
__global__ __launch_bounds__(256) void rope_inplace_k(u16* __restrict__ qkv) {
  int idx = blockIdx.x * 256 + threadIdx.x;
  int i = idx & 31;
  int h = (idx >> 5) & 15;
  int row = idx >> 9;
  int n = row & 2047;
  float invf = exp2f(-(float)i * 0.4152410118609203f);
  float ang = (float)n * invf;
  float c = cosf(ang), s = sinf(ang);
  size_t ibase = (size_t)row * 3072 + h * 64 + i;
  float x1 = bf2f(qkv[ibase]), x2 = bf2f(qkv[ibase + 32]);
  qkv[ibase] = f2bf((x1 * c - x2 * s) * 0.125f);
  qkv[ibase + 32] = f2bf((x2 * c + x1 * s) * 0.125f);
  x1 = bf2f(qkv[ibase + 1024]); x2 = bf2f(qkv[ibase + 1056]);
  qkv[ibase + 1024] = f2bf(x1 * c - x2 * s);
  qkv[ibase + 1056] = f2bf(x2 * c + x1 * s);
}

// ------- V transpose: qkv v-slice (n,64) -> vT (bh, 64, n), bf16 ---------------
__global__ __launch_bounds__(256) void transpose_v_k(const u16* __restrict__ qkv,
                                                     u16* __restrict__ vT) {
  __shared__ u16 tile[32][33];
  int bh = blockIdx.z;
  int b = bh >> 4, h = bh & 15;
  int n0 = blockIdx.x * 32, d0 = blockIdx.y * 32;
  int tx = threadIdx.x, ty = threadIdx.y;
#pragma unroll
  for (int i = 0; i < 32; i += 8)
    tile[ty + i][tx] =
        qkv[(size_t)(b * 2048 + n0 + ty + i) * 3072 + 2048 + h * 64 + d0 + tx];
  __syncthreads();
#pragma unroll
  for (int i = 0; i < 32; i += 8)
    vT[((size_t)bh * 64 + d0 + ty + i) * 2048 + n0 + tx] = tile[tx][ty + i];
}

// ------- flash attention (causal), paired q-tiles for load balance -------------
// block: q-tiles j and 31-j (64 rows each, wave w owns 16 rows of each).
// Loop kt=0..31-j staging K/V once; tile B=31-j consumes every kt, tile A=j
// consumes while kt<=j. Uniform 33 tile-computations per block.
#define LKT 72
__device__ __forceinline__ void attn_tile(const u16* lK, const u16* lV, u16* lp,
                                          const short8* aq, floatx4* o,
                                          float* m_i, float* l_i, int lr, int lq,
                                          bool diag, int qbase, int k0g) {
  floatx4 s[4];
#pragma unroll
  for (int ni = 0; ni < 4; ni++) {
    floatx4 accs = {};
#pragma unroll
    for (int kc = 0; kc < 2; kc++) {
      short8 bf = *(const short8*)&lK[(ni * 16 + lr) * LKT + kc * 32 + lq * 8];
      accs = __builtin_amdgcn_mfma_f32_16x16x32_bf16(aq[kc], bf, accs, 0, 0, 0);
    }
    s[ni] = accs;
  }
  if (diag) {
#pragma unroll
    for (int ni = 0; ni < 4; ni++) {
      int kg = k0g + ni * 16 + lr;
#pragma unroll
      for (int r = 0; r < 4; r++) {
        int qg = qbase + lq * 4 + r;
        if (kg > qg) s[ni][r] = -1e30f;
      }
    }
  }
  float mnew[4], alpha[4], psum[4];
#pragma unroll
  for (int r = 0; r < 4; r++) {
    float mx = fmaxf(fmaxf(s[0][r], s[1][r]), fmaxf(s[2][r], s[3][r]));
#pragma unroll
    for (int d = 1; d < 16; d <<= 1) mx = fmaxf(mx, __shfl_xor(mx, d, 64));
    mnew[r] = fmaxf(m_i[r], mx);
    alpha[r] = __expf(m_i[r] - mnew[r]);
    psum[r] = 0.0f;
  }
#pragma unroll
  for (int ni = 0; ni < 4; ni++)
#pragma unroll
    for (int r = 0; r < 4; r++) {
      float p = __expf(s[ni][r] - mnew[r]);
      s[ni][r] = p;
      psum[r] += p;
    }
#pragma unroll
  for (int r = 0; r < 4; r++) {
#pragma unroll
    for (int d = 1; d < 16; d <<= 1) psum[r] += __shfl_xor(psum[r], d, 64);
    l_i[r] = l_i[r] * alpha[r] + psum[r];
    m_i[r] = mnew[r];
  }
#pragma unroll
  for (int di = 0; di < 4; di++)
#pragma unroll
    for (int r = 0; r < 4; r++) o[di][r] *= alpha[r];
#pragma unroll
  for (int ni = 0; ni < 4; ni++)
#pragma unroll
    for (int r = 0; r < 4; r++)
      lp[(lq * 4 + r) * LKT + ni * 16 + lr] = f2bf(s[ni][r]);
  short8 pa0 = *(const short8*)&lp[lr * LKT + lq * 8];
  short8 pa1 = *(const short8*)&lp[lr * LKT + 32 + lq * 8];
#pragma unroll
  for (int di = 0; di < 4; di++) {
    short8 bv0 = *(const short8*)&lV[(di * 16 + lr) * LKT + lq * 8];
    o[di] = __builtin_amdgcn_mfma_f32_16x16x32_bf16(pa0, bv0, o[di], 0, 0, 0);
    short8 bv1 = *(const short8*)&lV[(di * 16 + lr) * LKT + 32 + lq * 8];
    o[di] = __builtin_amdgcn_mfma_f32_16x16x32_bf16(pa1, bv1, o[di], 0, 0, 0);
  }
}

__global__ __launch_bounds__(256) void attn_k(const u16* __restrict__ qkv,
                                              const u16* __restrict__ vt,
                                              u16* __restrict__ out) {
  __shared__ __align__(16) u16 lK[64 * LKT];
  __shared__ __align__(16) u16 lV[64 * LKT];
  __shared__ __align__(16) u16 lP[4][16 * LKT];
  int bh = blockIdx.y;
  int b = bh >> 4, h = bh & 15;
  int j = blockIdx.x;        // tile A = j, tile B = 31-j
  int jB = 31 - j;
  int tid = threadIdx.x;
  int w = tid >> 6, l = tid & 63;
  int lr = l & 15, lq = l >> 4;
  int q0A = j * 64, q0B = jB * 64;
  const u16* qb = qkv + (size_t)b * 2048 * 3072 + h * 64;
  const u16* kb = qkv + (size_t)b * 2048 * 3072 + 1024 + h * 64;
  const u16* vb = vt + (size_t)bh * 64 * 2048;
  int qrA = q0A + w * 16 + lr, qrB = q0B + w * 16 + lr;
  short8 aqA[2], aqB[2];
  aqA[0] = *(const short8*)(qb + (size_t)qrA * 3072 + lq * 8);
  aqA[1] = *(const short8*)(qb + (size_t)qrA * 3072 + 32 + lq * 8);
  aqB[0] = *(const short8*)(qb + (size_t)qrB * 3072 + lq * 8);
  aqB[1] = *(const short8*)(qb + (size_t)qrB * 3072 + 32 + lq * 8);
  floatx4 oA[4] = {}, oB[4] = {};
  float mA[4], lA_[4], mB[4], lB_[4];
#pragma unroll
  for (int r = 0; r < 4; r++) {
    mA[r] = -1e30f; lA_[r] = 0.0f; mB[r] = -1e30f; lB_[r] = 0.0f;
  }
  int st_row = tid >> 2, st_c = (tid & 3) * 16;
  u16* lp = &lP[w][0];
  for (int kt = 0; kt <= jB; ++kt) {
    {
      const u16* gk = kb + (size_t)(kt * 64 + st_row) * 3072 + st_c;
      short8 k0v = *(const short8*)gk;
      short8 k1v = *(const short8*)(gk + 8);
      const u16* gv = vb + (size_t)st_row * 2048 + kt * 64 + st_c;
      short8 v0v = *(const short8*)gv;
      short8 v1v = *(const short8*)(gv + 8);
      *(short8*)&lK[st_row * LKT + st_c] = k0v;
      *(short8*)&lK[st_row * LKT + st_c + 8] = k1v;
      *(short8*)&lV[st_row * LKT + st_c] = v0v;
      *(short8*)&lV[st_row * LKT + st_c + 8] = v1v;
    }
    __syncthreads();
    attn_tile(lK, lV, lp, aqB, oB, mB, lB_, lr, lq, kt == jB,
              q0B + w * 16, kt * 64);
    if (kt <= j)
      attn_tile(lK, lV, lp, aqA, oA, mA, lA_, lr, lq, kt == j,
                q0A + w * 16, kt * 64);
    __syncthreads();
  }
#pragma unroll
  for (int di = 0; di < 4; di++)
#pragma unroll
    for (int r = 0; r < 4; r++) {
      int qgA = q0A + w * 16 + lq * 4 + r;
      int qgB = q0B + w * 16 + lq * 4 + r;
      out[((size_t)(b * 2048 + qgA)) * 3072 + h * 64 + di * 16 + lr] =
          f2bf(oA[di][r] / lA_[r]);
      out[((size_t)(b * 2048 + qgB)) * 3072 + h * 64 + di * 16 + lr] =
          f2bf(oB[di][r] / lB_[r]);
    }
}

// ------- launch ---------------------------------------------------------------
extern "C" void kernel_launch(void* const* d_in, const int* in_sizes, int n_in,
                              void* d_out, int out_size, void* d_ws, size_t ws_size,
                              hipStream_t stream) {
  const float* x = (const float*)d_in[0];
  const float* gamma = (const float*)d_in[1];
  const float* beta = (const float*)d_in[2];
  const float* Wq = (const float*)d_in[3];
  const float* Wkv = (const float*)d_in[4];
  const float* Wo = (const float*)d_in[5];
  float* out = (float*)d_out;
  char* ws = (char*)d_ws;

  u16* qkv = (u16*)(ws);               // 4096x3072 bf16 = 24 MiB
  u16* wqkvT = (u16*)(ws + 25165824);  // 3072x1024 = 6 MiB
  u16* woT = (u16*)(ws + 31457280);    // 1024x1024 = 2 MiB
  u16* xn = (u16*)(ws + 33554432);     // 4096x1024 = 8 MiB
  u16* vT = xn;                        // alias: xn dead after GEMM1
  u16* attn_out = qkv + 2048;          // v-slice of qkv (dead after transpose_v)

  dim3 tb32(32, 8);
  transpose_w_k<<<dim3(32, 32), tb32, 0, stream>>>(Wq, wqkvT, 1024, 1024);
  transpose_w_k<<<dim3(64, 32), tb32, 0, stream>>>(Wkv, wqkvT + 1024 * 1024, 1024, 2048);
  transpose_w_k<<<dim3(32, 32), tb32, 0, stream>>>(Wo, woT, 1024, 1024);
  layernorm_k<<<4096, 256, 0, stream>>>(x, gamma, beta, xn);
  gemm_bf16_k<<<dim3(24, 32), 256, 0, stream>>>(xn, wqkvT, qkv, 1024, 1024, 3072, 0);
  rope_inplace_k<<<8192, 256, 0, stream>>>(qkv);
  transpose_v_k<<<dim3(64, 2, 32), tb32, 0, stream>>>(qkv, vT);
  attn_k<<<dim3(16, 32), 256, 0, stream>>>(qkv, vT, attn_out);
  gemm_bf16_k<<<dim3(8, 32), 256, 0, stream>>>(attn_out, woT, out, 1024, 3072, 1024, 1);
}